// Round 4
// baseline (576.924 us; speedup 1.0000x reference)
//
#include <hip/hip_runtime.h>
#include <math.h>

#define NNODES 50000
#define MPAD   50048            // 782 * 64
#define NFEAT  128
#define NEDGE  800000
#define ETOT   (NEDGE + NNODES) // 850000 edges incl. self-loops
#define H1     4
#define O1     256              // heads1 * hid1
#define C2     128
#define C3     10
#define NGRAPH 512

typedef __attribute__((ext_vector_type(8))) short short8;
typedef __attribute__((ext_vector_type(4))) float f32x4;

__device__ __forceinline__ unsigned short f2b(float f) {
  unsigned int u = __float_as_uint(f);
  u += 0x7fffu + ((u >> 16) & 1u);
  return (unsigned short)(u >> 16);
}
__device__ __forceinline__ float b2f(unsigned short u) {
  return __uint_as_float(((unsigned int)u) << 16);
}
__device__ __forceinline__ float readlane_f(float v, int l) {
  return __uint_as_float((unsigned)__builtin_amdgcn_readlane(__float_as_uint(v), l));
}

// ---------------- CSR build ----------------

__global__ void k_count(const int* __restrict__ dst_e, int* __restrict__ deg) {
  int e = blockIdx.x * 256 + threadIdx.x;
  if (e >= ETOT) return;
  int d = (e < NEDGE) ? dst_e[e] : (e - NEDGE);
  atomicAdd(&deg[d], 1);
}

__global__ __launch_bounds__(1024) void k_scan(const int* __restrict__ deg,
                                               int* __restrict__ rowptr,
                                               int* __restrict__ cursor) {
  __shared__ int wsum[16];
  __shared__ int carry_s;
  const int tid = threadIdx.x;
  const int lane = tid & 63, wid = tid >> 6;
  if (tid == 0) { carry_s = 0; rowptr[0] = 0; }
  __syncthreads();
  for (int base = 0; base < NNODES; base += 1024) {
    int idx = base + tid;
    int v = (idx < NNODES) ? deg[idx] : 0;
    int s = v;
#pragma unroll
    for (int off = 1; off < 64; off <<= 1) {
      int t = __shfl_up(s, off);
      if (lane >= off) s += t;
    }
    if (lane == 63) wsum[wid] = s;
    __syncthreads();
    int woff = carry_s;
#pragma unroll
    for (int k = 0; k < 16; ++k)
      if (k < wid) woff += wsum[k];
    int incl = woff + s;
    if (idx < NNODES) { rowptr[idx + 1] = incl; cursor[idx] = incl - v; }
    __syncthreads();
    if (tid == 1023) carry_s = incl;
    __syncthreads();
  }
}

__global__ void k_scatter(const int* __restrict__ src_e, const int* __restrict__ dst_e,
                          int* __restrict__ cursor, int* __restrict__ srcs) {
  int e = blockIdx.x * 256 + threadIdx.x;
  if (e >= ETOT) return;
  int d, s;
  if (e < NEDGE) { d = dst_e[e]; s = src_e[e]; }
  else           { d = e - NEDGE; s = e - NEDGE; }
  int pos = atomicAdd(&cursor[d], 1);
  srcs[pos] = s;
}

// ---------------- conversions / weight packing ----------------

__global__ void k_cvt(const float* __restrict__ X, unsigned short* __restrict__ Xb) {
  int idx = blockIdx.x * 256 + threadIdx.x;   // one per 4 elements of [MPAD][128]
  int base = idx * 4;
  if (base >= MPAD * NFEAT) return;
  int row = base >> 7;
  float4 v = make_float4(0.f, 0.f, 0.f, 0.f);
  if (row < NNODES) v = *(const float4*)(X + base);
  ushort4 o;
  o.x = f2b(v.x); o.y = f2b(v.y); o.z = f2b(v.z); o.w = f2b(v.w);
  *(ushort4*)(Xb + base) = o;
}

// Wp layout: [nt][ks][lane][8] so each lane's B fragment is one 16B load.
// element: k = ks*32 + (lane>>4)*8 + j ; n = nt*16 + (lane&15)
template<int K, int N>
__global__ void k_packW(const float* __restrict__ W, unsigned short* __restrict__ Wp,
                        int nsrc) {
  constexpr int KS = K / 32;
  int idx = blockIdx.x * 256 + threadIdx.x;
  if (idx >= K * N) return;
  int j = idx & 7;
  int lane = (idx >> 3) & 63;
  int t = idx >> 9;            // nt*KS + ks
  int ks = t % KS;
  int nt = t / KS;
  int k = ks * 32 + (lane >> 4) * 8 + j;
  int n = nt * 16 + (lane & 15);
  float v = (n < nsrc) ? W[(size_t)k * nsrc + n] : 0.f;
  Wp[idx] = f2b(v);
}

// ---------------- MFMA GEMM + fused attention-logit epilogue ----------------
// Hout[MPAD][N] (bf16) = Xb[MPAD][K] @ W[K][N]; als/ald[row][HEADS] = H·a_src / H·a_dst

template<int K, int N, int HEADS, int CREAL>
__global__ __launch_bounds__(256) void k_mm(const unsigned short* __restrict__ Xb,
                                            const unsigned short* __restrict__ Wp,
                                            unsigned short* __restrict__ Hout,
                                            const float* __restrict__ a_src,
                                            const float* __restrict__ a_dst,
                                            float* __restrict__ als,
                                            float* __restrict__ ald) {
  constexpr int KS = K / 32, NT = N / 16;
  constexpr int NTH = (NT + HEADS - 1) / HEADS;   // nts per head
  const int w = threadIdx.x >> 6, lane = threadIdx.x & 63;
  const int arow = blockIdx.x * 64 + w * 16 + (lane & 15);
  const int k0 = (lane >> 4) * 8;
  f32x4 acc[NT] = {};
  for (int ks = 0; ks < KS; ++ks) {
    short8 a = *(const short8*)(Xb + (size_t)arow * K + ks * 32 + k0);
    const short8* bp = (const short8*)Wp + (size_t)ks * 64 + lane;
#pragma unroll
    for (int nt = 0; nt < NT; ++nt) {
      short8 b = bp[(size_t)nt * KS * 64];
      acc[nt] = __builtin_amdgcn_mfma_f32_16x16x32_bf16(a, b, acc[nt], 0, 0, 0);
    }
  }
  const int col = lane & 15;
  const int rbase = blockIdx.x * 64 + w * 16 + (lane >> 4) * 4;
#pragma unroll
  for (int nt = 0; nt < NT; ++nt)
#pragma unroll
    for (int j = 0; j < 4; ++j)
      Hout[(size_t)(rbase + j) * N + nt * 16 + col] = f2b(acc[nt][j]);

  // fused attention logits: per-row dot with a_src/a_dst over channels (N dim)
  float av[NT], dv[NT];
#pragma unroll
  for (int nt = 0; nt < NT; ++nt) {
    int ch = nt * 16 + col;
    av[nt] = (ch < CREAL) ? a_src[ch] : 0.f;
    dv[nt] = (ch < CREAL) ? a_dst[ch] : 0.f;
  }
  float sa[HEADS][4], da[HEADS][4];
#pragma unroll
  for (int h = 0; h < HEADS; ++h)
#pragma unroll
    for (int j = 0; j < 4; ++j) { sa[h][j] = 0.f; da[h][j] = 0.f; }
#pragma unroll
  for (int nt = 0; nt < NT; ++nt) {
    int h = nt / NTH;
#pragma unroll
    for (int j = 0; j < 4; ++j) {
      sa[h][j] += acc[nt][j] * av[nt];
      da[h][j] += acc[nt][j] * dv[nt];
    }
  }
#pragma unroll
  for (int mask = 1; mask < 16; mask <<= 1)
#pragma unroll
    for (int h = 0; h < HEADS; ++h)
#pragma unroll
      for (int j = 0; j < 4; ++j) {
        sa[h][j] += __shfl_xor(sa[h][j], mask);
        da[h][j] += __shfl_xor(da[h][j], mask);
      }
  if (col == 0) {
#pragma unroll
    for (int j = 0; j < 4; ++j)
#pragma unroll
      for (int h = 0; h < HEADS; ++h) {
        als[(size_t)(rbase + j) * HEADS + h] = sa[h][j];
        ald[(size_t)(rbase + j) * HEADS + h] = da[h][j];
      }
  }
}

// ---------------- XCD-sliced softmax + aggregation (layers 1,2) ----------------
// Panel p = channels [p*CHP, (p+1)*CHP) of the row-major H buffer. All blocks of
// panel p have blockIdx%8==p -> same XCD (round-robin dispatch), so the panel's
// 64B-line slice (<=3.2MB) stays resident in that XCD's 4MB L2 and the 850K row
// gathers become L2 hits. Lanes: CHP/2 channel-pair lanes x ES edge slots.

template<int HEADS, int C, int SR, int CHP, bool ACT>
__global__ __launch_bounds__(256) void k_aggs(const int* __restrict__ rowptr,
                                              const int* __restrict__ srcs,
                                              const unsigned short* __restrict__ Hm,
                                              const float* __restrict__ als,
                                              const float* __restrict__ ald,
                                              const float* __restrict__ bias,
                                              unsigned short* __restrict__ outb) {
  constexpr int TOT = HEADS * C;
  constexpr int LPS = CHP / 2;           // lanes per edge-slot (each lane: 2 ch)
  constexpr int ES  = 64 / LPS;          // independent edge slots per wave
  const int p = blockIdx.x & 7;
  const int n = (blockIdx.x >> 3) * 4 + (threadIdx.x >> 6);
  const int lane = threadIdx.x & 63;
  const int head = (p * CHP) / C;
  const int chbase = p * CHP + (lane % LPS) * 2;
  const int eslot = lane / LPS;
  const int r0 = rowptr[n], r1 = rowptr[n + 1];
  const float aldm = ald[(size_t)n * HEADS + head];
  float acc0 = 0.f, acc1 = 0.f, den = 0.f;
#pragma unroll 2
  for (int i = r0 + eslot; i < r1; i += ES) {
    int s = srcs[i];
    float ev = als[(size_t)s * HEADS + head] + aldm;
    ev = (ev > 0.f) ? ev : 0.2f * ev;
    float ex = __expf(ev);
    den += ex;
    ushort2 hv = *(const ushort2*)(Hm + (size_t)s * SR + chbase);
    acc0 += ex * b2f(hv.x);
    acc1 += ex * b2f(hv.y);
  }
#pragma unroll
  for (int mask = LPS; mask < 64; mask <<= 1) {
    acc0 += __shfl_xor(acc0, mask);
    acc1 += __shfl_xor(acc1, mask);
    den  += __shfl_xor(den, mask);
  }
  if (eslot == 0) {
    float rden = 1.f / (den + 1e-16f);
    float v0 = acc0 * rden + bias[chbase];
    float v1 = acc1 * rden + bias[chbase + 1];
    if (ACT) { v0 = (v0 > 0.f) ? v0 : 0.01f * v0; v1 = (v1 > 0.f) ? v1 : 0.01f * v1; }
    ushort2 o; o.x = f2b(v0); o.y = f2b(v1);
    *(ushort2*)(outb + (size_t)n * TOT + chbase) = o;
  }
}

// ---------------- layer-3 aggregation + fused global_add_pool ----------------
// Per chunk of 64 edges, each lane precomputes exp for one edge; inner loop
// broadcasts via readlane and gathers the 10-channel row (lane<10 active).

__global__ __launch_bounds__(256) void k_agg3(const int* __restrict__ rowptr,
                                              const int* __restrict__ srcs,
                                              const unsigned short* __restrict__ Hm,
                                              const float* __restrict__ als,
                                              const float* __restrict__ ald,
                                              const float* __restrict__ bias,
                                              float* __restrict__ pooled,
                                              const int* __restrict__ batch) {
  const int n = blockIdx.x * 4 + (threadIdx.x >> 6);
  const int lane = threadIdx.x & 63;
  const int r0 = rowptr[n], r1 = rowptr[n + 1];
  const float aldm = ald[n];
  float acc = 0.f, den = 0.f;
  for (int i0 = r0; i0 < r1; i0 += 64) {
    const int take = min(64, r1 - i0);
    int sidx = srcs[min(i0 + lane, r1 - 1)];
    float ev = als[sidx] + aldm;
    ev = (ev > 0.f) ? ev : 0.2f * ev;
    float exv = (lane < take) ? __expf(ev) : 0.f;
    den += exv;
#pragma unroll 8
    for (int m = 0; m < take; ++m) {
      int s = __builtin_amdgcn_readlane(sidx, m);
      float ex = readlane_f(exv, m);
      if (lane < C3) acc += ex * b2f(Hm[(size_t)s * 16 + lane]);
    }
  }
#pragma unroll
  for (int mask = 1; mask < 64; mask <<= 1) den += __shfl_xor(den, mask);
  if (lane < C3) {
    float val = acc / (den + 1e-16f) + bias[lane];
    atomicAdd(&pooled[(size_t)batch[n] * C3 + lane], val);
  }
}

// ---------------- log_softmax ----------------

__global__ void k_lsm(const float* __restrict__ pooled, float* __restrict__ dout) {
  int g = blockIdx.x * 256 + threadIdx.x;
  if (g >= NGRAPH) return;
  float v[C3];
  float mx = -1e30f;
#pragma unroll
  for (int c = 0; c < C3; ++c) { v[c] = pooled[g * C3 + c]; mx = fmaxf(mx, v[c]); }
  float ssum = 0.f;
#pragma unroll
  for (int c = 0; c < C3; ++c) ssum += __expf(v[c] - mx);
  float lse = mx + __logf(ssum);
#pragma unroll
  for (int c = 0; c < C3; ++c) {
    dout[g * C3 + c] = v[c] - lse;               // log_softmax
    dout[NGRAPH * C3 + g * C3 + c] = v[c];       // pooled
  }
}

// ---------------- launcher ----------------

extern "C" void kernel_launch(void* const* d_in, const int* in_sizes, int n_in,
                              void* d_out, int out_size, void* d_ws, size_t ws_size,
                              hipStream_t stream) {
  (void)in_sizes; (void)n_in; (void)out_size; (void)ws_size;
  const float* x     = (const float*)d_in[0];
  const int*   eix   = (const int*)d_in[1];
  const int*   batch = (const int*)d_in[3];
  const float* W1 = (const float*)d_in[4];
  const float* as1 = (const float*)d_in[5];
  const float* ad1 = (const float*)d_in[6];
  const float* b1 = (const float*)d_in[7];
  const float* W2 = (const float*)d_in[8];
  const float* as2 = (const float*)d_in[9];
  const float* ad2 = (const float*)d_in[10];
  const float* b2 = (const float*)d_in[11];
  const float* W3 = (const float*)d_in[12];
  const float* as3 = (const float*)d_in[13];
  const float* ad3 = (const float*)d_in[14];
  const float* b3 = (const float*)d_in[15];
  const int* src_e = eix;
  const int* dst_e = eix + NEDGE;

  char* ws = (char*)d_ws;
  size_t off = 0;
  auto carve = [&](size_t bytes) -> char* {
    char* p = ws + off;
    off += (bytes + 511) & ~(size_t)511;
    return p;
  };
  int* deg    = (int*)carve((size_t)NNODES * 4);
  int* rowptr = (int*)carve((size_t)(NNODES + 1) * 4);
  int* cursor = (int*)carve((size_t)NNODES * 4);
  int* srcs   = (int*)carve((size_t)ETOT * 4);
  float* als  = (float*)carve((size_t)MPAD * H1 * 4);
  float* ald  = (float*)carve((size_t)MPAD * H1 * 4);
  unsigned short* Xb  = (unsigned short*)carve((size_t)MPAD * NFEAT * 2);
  unsigned short* Hb  = (unsigned short*)carve((size_t)MPAD * O1 * 2);
  unsigned short* Xc  = (unsigned short*)carve((size_t)MPAD * O1 * 2);
  unsigned short* H3b = (unsigned short*)carve((size_t)MPAD * 16 * 2);
  float* pooled = (float*)carve((size_t)NGRAPH * C3 * 4);
  unsigned short* W1p = (unsigned short*)carve((size_t)NFEAT * O1 * 2);
  unsigned short* W2p = (unsigned short*)carve((size_t)O1 * C2 * 2);
  unsigned short* W3p = (unsigned short*)carve((size_t)C2 * 16 * 2);

  hipMemsetAsync(deg, 0, (size_t)NNODES * 4, stream);
  hipMemsetAsync(pooled, 0, (size_t)NGRAPH * C3 * 4, stream);

  // CSR by destination (shared across layers), storing src ids directly
  k_count  <<<(ETOT + 255) / 256, 256, 0, stream>>>(dst_e, deg);
  k_scan   <<<1, 1024, 0, stream>>>(deg, rowptr, cursor);
  k_scatter<<<(ETOT + 255) / 256, 256, 0, stream>>>(src_e, dst_e, cursor, srcs);

  // input conversion + weight packing
  k_cvt<<<(MPAD * NFEAT / 4 + 255) / 256, 256, 0, stream>>>(x, Xb);
  k_packW<NFEAT, O1><<<(NFEAT * O1 + 255) / 256, 256, 0, stream>>>(W1, W1p, O1);
  k_packW<O1, C2><<<(O1 * C2 + 255) / 256, 256, 0, stream>>>(W2, W2p, C2);
  k_packW<C2, 16><<<(C2 * 16 + 255) / 256, 256, 0, stream>>>(W3, W3p, C3);

  const int GB = MPAD / 64;        // 782 gemm blocks
  const int NB = NNODES / 4;       // 12500 node groups
  const int NBS = NB * 8;          // x 8 channel panels (XCD-sliced)

  // conv1: 128 -> 4x64 (concat 256), leaky_relu(0.01)
  k_mm<NFEAT, O1, H1, O1><<<GB, 256, 0, stream>>>(Xb, W1p, Hb, as1, ad1, als, ald);
  k_aggs<H1, 64, O1, 32, true><<<NBS, 256, 0, stream>>>(rowptr, srcs, Hb, als, ald, b1, Xc);

  // conv2: 256 -> 128, leaky_relu(0.01)
  k_mm<O1, C2, 1, C2><<<GB, 256, 0, stream>>>(Xc, W2p, Hb, as2, ad2, als, ald);
  k_aggs<1, C2, C2, 16, true><<<NBS, 256, 0, stream>>>(rowptr, srcs, Hb, als, ald, b2, Xc);

  // conv3: 128 -> 10 (padded to 16), no activation, fused pool
  k_mm<C2, 16, 1, C3><<<GB, 256, 0, stream>>>(Xc, W3p, H3b, as3, ad3, als, ald);
  k_agg3<<<NB, 256, 0, stream>>>(rowptr, srcs, H3b, als, ald, b3, pooled, batch);

  // log_softmax; output = [log_softmax | pooled]
  k_lsm<<<(NGRAPH + 255) / 256, 256, 0, stream>>>(pooled, (float*)d_out);
}

// Round 5
// 432.025 us; speedup vs baseline: 1.3354x; 1.3354x over previous
//
#include <hip/hip_runtime.h>
#include <math.h>

#define NNODES 50000
#define MPAD   50048            // 782 * 64
#define NFEAT  128
#define NEDGE  800000
#define ETOT   (NEDGE + NNODES) // 850000 edges incl. self-loops
#define H1     4
#define O1     256              // heads1 * hid1
#define C2     128
#define C3     10
#define NGRAPH 512

typedef __attribute__((ext_vector_type(8))) short short8;
typedef __attribute__((ext_vector_type(4))) float f32x4;

__device__ __forceinline__ unsigned short f2b(float f) {
  unsigned int u = __float_as_uint(f);
  u += 0x7fffu + ((u >> 16) & 1u);
  return (unsigned short)(u >> 16);
}
__device__ __forceinline__ float b2f(unsigned short u) {
  return __uint_as_float(((unsigned int)u) << 16);
}
__device__ __forceinline__ float readlane_f(float v, int l) {
  return __uint_as_float((unsigned)__builtin_amdgcn_readlane(__float_as_uint(v), l));
}

// ---------------- CSR build ----------------

__global__ void k_count(const int* __restrict__ dst_e, int* __restrict__ deg) {
  int e = blockIdx.x * 256 + threadIdx.x;
  if (e >= ETOT) return;
  int d = (e < NEDGE) ? dst_e[e] : (e - NEDGE);
  atomicAdd(&deg[d], 1);
}

__global__ __launch_bounds__(1024) void k_scan(const int* __restrict__ deg,
                                               int* __restrict__ rowptr,
                                               int* __restrict__ cursor) {
  __shared__ int wsum[16];
  __shared__ int carry_s;
  const int tid = threadIdx.x;
  const int lane = tid & 63, wid = tid >> 6;
  if (tid == 0) { carry_s = 0; rowptr[0] = 0; }
  __syncthreads();
  for (int base = 0; base < NNODES; base += 1024) {
    int idx = base + tid;
    int v = (idx < NNODES) ? deg[idx] : 0;
    int s = v;
#pragma unroll
    for (int off = 1; off < 64; off <<= 1) {
      int t = __shfl_up(s, off);
      if (lane >= off) s += t;
    }
    if (lane == 63) wsum[wid] = s;
    __syncthreads();
    int woff = carry_s;
#pragma unroll
    for (int k = 0; k < 16; ++k)
      if (k < wid) woff += wsum[k];
    int incl = woff + s;
    if (idx < NNODES) { rowptr[idx + 1] = incl; cursor[idx] = incl - v; }
    __syncthreads();
    if (tid == 1023) carry_s = incl;
    __syncthreads();
  }
}

__global__ void k_scatter(const int* __restrict__ src_e, const int* __restrict__ dst_e,
                          int* __restrict__ cursor, int* __restrict__ srcs) {
  int e = blockIdx.x * 256 + threadIdx.x;
  if (e >= ETOT) return;
  int d, s;
  if (e < NEDGE) { d = dst_e[e]; s = src_e[e]; }
  else           { d = e - NEDGE; s = e - NEDGE; }
  int pos = atomicAdd(&cursor[d], 1);
  srcs[pos] = s;
}

// ---------------- L3 primer: streaming read, kept alive via empty asm ------

__global__ void k_prime(const float4* __restrict__ p, int n4) {
  for (int i = blockIdx.x * 256 + threadIdx.x; i < n4; i += gridDim.x * 256) {
    float4 v = p[i];
    asm volatile("" :: "v"(v.x), "v"(v.y), "v"(v.z), "v"(v.w));
  }
}

// ---------------- layer-1 prep: was/wad[h][k] = sum_j W1[k, h*64+j]*a[h][j] --

__global__ void k_prep(const float* __restrict__ W1, const float* __restrict__ as1,
                       const float* __restrict__ ad1,
                       float* __restrict__ was, float* __restrict__ wad) {
  int tid = threadIdx.x;          // 512 = 4 heads x 128 k
  int h = tid >> 7, k = tid & 127;
  float s = 0.f, d = 0.f;
  for (int j = 0; j < 64; ++j) {
    float w = W1[(size_t)k * 256 + h * 64 + j];
    s += w * as1[h * 64 + j];
    d += w * ad1[h * 64 + j];
  }
  was[h * 128 + k] = s;
  wad[h * 128 + k] = d;
}

// ---------------- cvt X->bf16 + layer-1 logits (als1/ald1 = X . was/wad) ----

__global__ __launch_bounds__(256) void k_cvt2(const float* __restrict__ X,
                                              unsigned short* __restrict__ Xb,
                                              const float* __restrict__ was,
                                              const float* __restrict__ wad,
                                              float* __restrict__ als,
                                              float* __restrict__ ald) {
  const int n = blockIdx.x * 4 + (threadIdx.x >> 6);
  const int lane = threadIdx.x & 63;
  const int k0 = lane * 2;
  float2 xv = *(const float2*)(X + (size_t)n * 128 + k0);
  ushort2 o; o.x = f2b(xv.x); o.y = f2b(xv.y);
  *(ushort2*)(Xb + (size_t)n * 128 + k0) = o;
  float s[4], d[4];
#pragma unroll
  for (int h = 0; h < 4; ++h) {
    float2 ws = *(const float2*)(was + h * 128 + k0);
    float2 wd = *(const float2*)(wad + h * 128 + k0);
    s[h] = xv.x * ws.x + xv.y * ws.y;
    d[h] = xv.x * wd.x + xv.y * wd.y;
  }
#pragma unroll
  for (int m = 1; m < 64; m <<= 1)
#pragma unroll
    for (int h = 0; h < 4; ++h) { s[h] += __shfl_xor(s[h], m); d[h] += __shfl_xor(d[h], m); }
  if (lane == 0) {
#pragma unroll
    for (int h = 0; h < 4; ++h) {
      als[(size_t)n * 4 + h] = s[h];
      ald[(size_t)n * 4 + h] = d[h];
    }
  }
}

// ---------------- weight packing ----------------
// Wp layout: [nt][ks][lane][8]; k = ks*32 + (lane>>4)*8 + j ; n = nt*16 + (lane&15)

template<int K, int N>
__global__ void k_packW(const float* __restrict__ W, unsigned short* __restrict__ Wp,
                        int nsrc) {
  constexpr int KS = K / 32;
  int idx = blockIdx.x * 256 + threadIdx.x;
  if (idx >= K * N) return;
  int j = idx & 7;
  int lane = (idx >> 3) & 63;
  int t = idx >> 9;
  int ks = t % KS;
  int nt = t / KS;
  int k = ks * 32 + (lane >> 4) * 8 + j;
  int n = nt * 16 + (lane & 15);
  float v = (n < nsrc) ? W[(size_t)k * nsrc + n] : 0.f;
  Wp[idx] = f2b(v);
}

// per-head pack of W1 (K=128, 4 heads x N=64): Wp1[h][nt][ks][lane][8]
__global__ void k_packW1(const float* __restrict__ W, unsigned short* __restrict__ Wp) {
  int idx = blockIdx.x * 256 + threadIdx.x;
  if (idx >= 4 * 8192) return;
  int h = idx >> 13, r = idx & 8191;
  int j = r & 7, lane = (r >> 3) & 63, t = r >> 9;
  int ks = t & 3, nt = t >> 2;
  int k = ks * 32 + (lane >> 4) * 8 + j;
  int n = nt * 16 + (lane & 15);
  Wp[idx] = f2b(W[(size_t)k * 256 + h * 64 + n]);
}

// ---------------- layer-1 pre-GEMM aggregation over X^ (128 ch, 4 heads) ----
// P[n][h][:] = (sum_e exp(lrelu(als[s,h]+ald[n,h])) * X^[s]) / den_h

__global__ __launch_bounds__(256) void k_aggP(const int* __restrict__ rowptr,
                                              const int* __restrict__ srcs,
                                              const unsigned short* __restrict__ Xb,
                                              const float* __restrict__ als,
                                              const float* __restrict__ ald,
                                              unsigned short* __restrict__ P) {
  const int n = blockIdx.x * 4 + (threadIdx.x >> 6);
  const int lane = threadIdx.x & 63;
  const int r0 = rowptr[n], r1 = rowptr[n + 1];
  const int e_lane = lane & 15;
  const float aldv = ald[(size_t)n * 4 + (lane >> 4)];
  const int ch0 = lane * 2;
  float a00 = 0.f, a01 = 0.f, a10 = 0.f, a11 = 0.f;
  float a20 = 0.f, a21 = 0.f, a30 = 0.f, a31 = 0.f;
  float den = 0.f;
  for (int i0 = r0; i0 < r1; i0 += 16) {
    const int take = min(16, r1 - i0);
    int sidx = srcs[min(i0 + e_lane, r1 - 1)];
    float ev = als[(size_t)sidx * 4 + (lane >> 4)] + aldv;
    ev = (ev > 0.f) ? ev : 0.2f * ev;
    float exv = (e_lane < take) ? __expf(ev) : 0.f;
    den += exv;
#pragma unroll 4
    for (int m = 0; m < take; ++m) {
      int s = __builtin_amdgcn_readlane(sidx, m);
      float w0 = readlane_f(exv, m);
      float w1 = readlane_f(exv, m + 16);
      float w2 = readlane_f(exv, m + 32);
      float w3 = readlane_f(exv, m + 48);
      ushort2 hv = *(const ushort2*)(Xb + (size_t)s * 128 + ch0);
      float x0 = b2f(hv.x), x1 = b2f(hv.y);
      a00 += w0 * x0; a01 += w0 * x1;
      a10 += w1 * x0; a11 += w1 * x1;
      a20 += w2 * x0; a21 += w2 * x1;
      a30 += w3 * x0; a31 += w3 * x1;
    }
  }
#pragma unroll
  for (int m = 1; m < 16; m <<= 1) den += __shfl_xor(den, m);
  float acc[4][2] = {{a00,a01},{a10,a11},{a20,a21},{a30,a31}};
#pragma unroll
  for (int h = 0; h < 4; ++h) {
    float rd = 1.f / (readlane_f(den, h * 16) + 1e-16f);
    ushort2 o; o.x = f2b(acc[h][0] * rd); o.y = f2b(acc[h][1] * rd);
    *(ushort2*)(P + ((size_t)n * 4 + h) * 128 + ch0) = o;
  }
}

// ---------------- per-head GEMM: act1[:, h*64..] = lrelu(P_h @ W1_h + b1) ----

__global__ __launch_bounds__(256) void k_mmh(const unsigned short* __restrict__ P,
                                             const unsigned short* __restrict__ Wp,
                                             const float* __restrict__ b1,
                                             unsigned short* __restrict__ act1) {
  const int hy = blockIdx.y;
  const int w = threadIdx.x >> 6, lane = threadIdx.x & 63;
  const int arow = blockIdx.x * 64 + w * 16 + (lane & 15);
  const int k0 = (lane >> 4) * 8;
  const unsigned short* Ab = P + ((size_t)arow * 4 + hy) * 128;
  f32x4 acc[4] = {};
#pragma unroll
  for (int ks = 0; ks < 4; ++ks) {
    short8 a = *(const short8*)(Ab + ks * 32 + k0);
    const short8* bp = (const short8*)(Wp + (size_t)hy * 8192) + ks * 64 + lane;
#pragma unroll
    for (int nt = 0; nt < 4; ++nt) {
      short8 b = bp[(size_t)nt * 4 * 64];
      acc[nt] = __builtin_amdgcn_mfma_f32_16x16x32_bf16(a, b, acc[nt], 0, 0, 0);
    }
  }
  const int col = lane & 15;
  const int rbase = blockIdx.x * 64 + w * 16 + (lane >> 4) * 4;
#pragma unroll
  for (int nt = 0; nt < 4; ++nt) {
    int ch = hy * 64 + nt * 16 + col;
    float bb = b1[ch];
#pragma unroll
    for (int j = 0; j < 4; ++j) {
      float v = acc[nt][j] + bb;
      v = (v > 0.f) ? v : 0.01f * v;
      act1[(size_t)(rbase + j) * 256 + ch] = f2b(v);
    }
  }
}

// ---------------- MFMA GEMM + fused attention-logit epilogue (layers 2,3) ---

template<int K, int N, int HEADS, int CREAL>
__global__ __launch_bounds__(256) void k_mm(const unsigned short* __restrict__ Xb,
                                            const unsigned short* __restrict__ Wp,
                                            unsigned short* __restrict__ Hout,
                                            const float* __restrict__ a_src,
                                            const float* __restrict__ a_dst,
                                            float* __restrict__ als,
                                            float* __restrict__ ald) {
  constexpr int KS = K / 32, NT = N / 16;
  constexpr int NTH = (NT + HEADS - 1) / HEADS;
  const int w = threadIdx.x >> 6, lane = threadIdx.x & 63;
  const int arow = blockIdx.x * 64 + w * 16 + (lane & 15);
  const int k0 = (lane >> 4) * 8;
  f32x4 acc[NT] = {};
  for (int ks = 0; ks < KS; ++ks) {
    short8 a = *(const short8*)(Xb + (size_t)arow * K + ks * 32 + k0);
    const short8* bp = (const short8*)Wp + (size_t)ks * 64 + lane;
#pragma unroll
    for (int nt = 0; nt < NT; ++nt) {
      short8 b = bp[(size_t)nt * KS * 64];
      acc[nt] = __builtin_amdgcn_mfma_f32_16x16x32_bf16(a, b, acc[nt], 0, 0, 0);
    }
  }
  const int col = lane & 15;
  const int rbase = blockIdx.x * 64 + w * 16 + (lane >> 4) * 4;
#pragma unroll
  for (int nt = 0; nt < NT; ++nt)
#pragma unroll
    for (int j = 0; j < 4; ++j)
      Hout[(size_t)(rbase + j) * N + nt * 16 + col] = f2b(acc[nt][j]);

  float av[NT], dv[NT];
#pragma unroll
  for (int nt = 0; nt < NT; ++nt) {
    int ch = nt * 16 + col;
    av[nt] = (ch < CREAL) ? a_src[ch] : 0.f;
    dv[nt] = (ch < CREAL) ? a_dst[ch] : 0.f;
  }
  float sa[HEADS][4], da[HEADS][4];
#pragma unroll
  for (int h = 0; h < HEADS; ++h)
#pragma unroll
    for (int j = 0; j < 4; ++j) { sa[h][j] = 0.f; da[h][j] = 0.f; }
#pragma unroll
  for (int nt = 0; nt < NT; ++nt) {
    int h = nt / NTH;
#pragma unroll
    for (int j = 0; j < 4; ++j) {
      sa[h][j] += acc[nt][j] * av[nt];
      da[h][j] += acc[nt][j] * dv[nt];
    }
  }
#pragma unroll
  for (int mask = 1; mask < 16; mask <<= 1)
#pragma unroll
    for (int h = 0; h < HEADS; ++h)
#pragma unroll
      for (int j = 0; j < 4; ++j) {
        sa[h][j] += __shfl_xor(sa[h][j], mask);
        da[h][j] += __shfl_xor(da[h][j], mask);
      }
  if (col == 0) {
#pragma unroll
    for (int j = 0; j < 4; ++j)
#pragma unroll
      for (int h = 0; h < HEADS; ++h) {
        als[(size_t)(rbase + j) * HEADS + h] = sa[h][j];
        ald[(size_t)(rbase + j) * HEADS + h] = da[h][j];
      }
  }
}

// ---------------- softmax + aggregation, one wave per dst node (layer 2) ----

template<int C, bool ACT>
__global__ __launch_bounds__(256) void k_agg(const int* __restrict__ rowptr,
                                             const int* __restrict__ srcs,
                                             const unsigned short* __restrict__ Hm,
                                             const float* __restrict__ als,
                                             const float* __restrict__ ald,
                                             const float* __restrict__ bias,
                                             unsigned short* __restrict__ outb) {
  const int n = blockIdx.x * 4 + (threadIdx.x >> 6);
  const int lane = threadIdx.x & 63;
  const int r0 = rowptr[n], r1 = rowptr[n + 1];
  const int ch0 = lane * 2;
  const float aldm = ald[n];
  float acc0 = 0.f, acc1 = 0.f, den = 0.f;
  for (int i0 = r0; i0 < r1; i0 += 64) {
    const int take = min(64, r1 - i0);
    int sidx = srcs[min(i0 + lane, r1 - 1)];
    float ev = als[sidx] + aldm;
    ev = (ev > 0.f) ? ev : 0.2f * ev;
    float exv = (lane < take) ? __expf(ev) : 0.f;
    den += exv;
#pragma unroll 8
    for (int m = 0; m < take; ++m) {
      int s = __builtin_amdgcn_readlane(sidx, m);
      float ex = readlane_f(exv, m);
      ushort2 hv = *(const ushort2*)(Hm + (size_t)s * C + ch0);
      acc0 += ex * b2f(hv.x);
      acc1 += ex * b2f(hv.y);
    }
  }
#pragma unroll
  for (int mask = 1; mask < 64; mask <<= 1) den += __shfl_xor(den, mask);
  float rden = 1.f / (den + 1e-16f);
  float v0 = acc0 * rden + bias[ch0];
  float v1 = acc1 * rden + bias[ch0 + 1];
  if (ACT) { v0 = (v0 > 0.f) ? v0 : 0.01f * v0; v1 = (v1 > 0.f) ? v1 : 0.01f * v1; }
  ushort2 o; o.x = f2b(v0); o.y = f2b(v1);
  *(ushort2*)(outb + (size_t)n * C + ch0) = o;
}

// ---------------- layer-3 aggregation + fused global_add_pool ----------------

__global__ __launch_bounds__(256) void k_agg3(const int* __restrict__ rowptr,
                                              const int* __restrict__ srcs,
                                              const unsigned short* __restrict__ Hm,
                                              const float* __restrict__ als,
                                              const float* __restrict__ ald,
                                              const float* __restrict__ bias,
                                              float* __restrict__ pooled,
                                              const int* __restrict__ batch) {
  const int n = blockIdx.x * 4 + (threadIdx.x >> 6);
  const int lane = threadIdx.x & 63;
  const int r0 = rowptr[n], r1 = rowptr[n + 1];
  const float aldm = ald[n];
  float acc = 0.f, den = 0.f;
  for (int i0 = r0; i0 < r1; i0 += 64) {
    const int take = min(64, r1 - i0);
    int sidx = srcs[min(i0 + lane, r1 - 1)];
    float ev = als[sidx] + aldm;
    ev = (ev > 0.f) ? ev : 0.2f * ev;
    float exv = (lane < take) ? __expf(ev) : 0.f;
    den += exv;
#pragma unroll 8
    for (int m = 0; m < take; ++m) {
      int s = __builtin_amdgcn_readlane(sidx, m);
      float ex = readlane_f(exv, m);
      if (lane < C3) acc += ex * b2f(Hm[(size_t)s * 16 + lane]);
    }
  }
#pragma unroll
  for (int mask = 1; mask < 64; mask <<= 1) den += __shfl_xor(den, mask);
  if (lane < C3) {
    float val = acc / (den + 1e-16f) + bias[lane];
    atomicAdd(&pooled[(size_t)batch[n] * C3 + lane], val);
  }
}

// ---------------- log_softmax ----------------

__global__ void k_lsm(const float* __restrict__ pooled, float* __restrict__ dout) {
  int g = blockIdx.x * 256 + threadIdx.x;
  if (g >= NGRAPH) return;
  float v[C3];
  float mx = -1e30f;
#pragma unroll
  for (int c = 0; c < C3; ++c) { v[c] = pooled[g * C3 + c]; mx = fmaxf(mx, v[c]); }
  float ssum = 0.f;
#pragma unroll
  for (int c = 0; c < C3; ++c) ssum += __expf(v[c] - mx);
  float lse = mx + __logf(ssum);
#pragma unroll
  for (int c = 0; c < C3; ++c) {
    dout[g * C3 + c] = v[c] - lse;
    dout[NGRAPH * C3 + g * C3 + c] = v[c];
  }
}

// ---------------- launcher ----------------

extern "C" void kernel_launch(void* const* d_in, const int* in_sizes, int n_in,
                              void* d_out, int out_size, void* d_ws, size_t ws_size,
                              hipStream_t stream) {
  (void)in_sizes; (void)n_in; (void)out_size; (void)ws_size;
  const float* x     = (const float*)d_in[0];
  const int*   eix   = (const int*)d_in[1];
  const int*   batch = (const int*)d_in[3];
  const float* W1 = (const float*)d_in[4];
  const float* as1 = (const float*)d_in[5];
  const float* ad1 = (const float*)d_in[6];
  const float* b1 = (const float*)d_in[7];
  const float* W2 = (const float*)d_in[8];
  const float* as2 = (const float*)d_in[9];
  const float* ad2 = (const float*)d_in[10];
  const float* b2 = (const float*)d_in[11];
  const float* W3 = (const float*)d_in[12];
  const float* as3 = (const float*)d_in[13];
  const float* ad3 = (const float*)d_in[14];
  const float* b3 = (const float*)d_in[15];
  const int* src_e = eix;
  const int* dst_e = eix + NEDGE;

  char* ws = (char*)d_ws;
  size_t off = 0;
  auto carve = [&](size_t bytes) -> char* {
    char* p = ws + off;
    off += (bytes + 511) & ~(size_t)511;
    return p;
  };
  int* deg    = (int*)carve((size_t)NNODES * 4);
  int* rowptr = (int*)carve((size_t)(NNODES + 1) * 4);
  int* cursor = (int*)carve((size_t)NNODES * 4);
  int* srcs   = (int*)carve((size_t)ETOT * 4);
  float* als  = (float*)carve((size_t)MPAD * H1 * 4);
  float* ald  = (float*)carve((size_t)MPAD * H1 * 4);
  float* was  = (float*)carve((size_t)512 * 4);
  float* wad  = (float*)carve((size_t)512 * 4);
  unsigned short* Xb   = (unsigned short*)carve((size_t)MPAD * 128 * 2);
  unsigned short* P    = (unsigned short*)carve((size_t)MPAD * 512 * 2);
  unsigned short* act1 = (unsigned short*)carve((size_t)MPAD * 256 * 2);
  unsigned short* Hb   = (unsigned short*)carve((size_t)MPAD * 128 * 2);
  unsigned short* Xc   = (unsigned short*)carve((size_t)MPAD * 128 * 2);
  unsigned short* H3b  = (unsigned short*)carve((size_t)MPAD * 16 * 2);
  float* pooled = (float*)carve((size_t)NGRAPH * C3 * 4);
  unsigned short* W1p = (unsigned short*)carve((size_t)4 * 8192 * 2);
  unsigned short* W2p = (unsigned short*)carve((size_t)O1 * C2 * 2);
  unsigned short* W3p = (unsigned short*)carve((size_t)C2 * 16 * 2);

  hipMemsetAsync(deg, 0, (size_t)NNODES * 4, stream);
  hipMemsetAsync(pooled, 0, (size_t)NGRAPH * C3 * 4, stream);

  // CSR by destination (shared across layers)
  k_count  <<<(ETOT + 255) / 256, 256, 0, stream>>>(dst_e, deg);
  k_scan   <<<1, 1024, 0, stream>>>(deg, rowptr, cursor);
  k_scatter<<<(ETOT + 255) / 256, 256, 0, stream>>>(src_e, dst_e, cursor, srcs);

  // prep + conversion + packing
  k_prep<<<1, 512, 0, stream>>>(W1, as1, ad1, was, wad);
  k_cvt2<<<NNODES / 4, 256, 0, stream>>>(x, Xb, was, wad, als, ald);
  k_packW1<<<(4 * 8192 + 255) / 256, 256, 0, stream>>>(W1, W1p);
  k_packW<O1, C2><<<(O1 * C2 + 255) / 256, 256, 0, stream>>>(W2, W2p, C2);
  k_packW<C2, 16><<<(C2 * 16 + 255) / 256, 256, 0, stream>>>(W3, W3p, C3);

  const int GB = MPAD / 64;        // 782 gemm blocks
  const int NB = NNODES / 4;       // 12500 node groups

  // layer 1: aggregate X^ in the 128-ch basis (4 heads), then per-head GEMM
  k_prime<<<2048, 256, 0, stream>>>((const float4*)Xb, MPAD * 16);
  k_aggP<<<NB, 256, 0, stream>>>(rowptr, srcs, Xb, als, ald, P);
  k_mmh<<<dim3(GB, 4), 256, 0, stream>>>(P, W1p, b1, act1);

  // layer 2: GEMM (256->128) + logits, prime, aggregate
  k_mm<O1, C2, 1, C2><<<GB, 256, 0, stream>>>(act1, W2p, Hb, as2, ad2, als, ald);
  k_prime<<<2048, 256, 0, stream>>>((const float4*)Hb, MPAD * 16);
  k_agg<C2, true><<<NB, 256, 0, stream>>>(rowptr, srcs, Hb, als, ald, b2, Xc);

  // layer 3: GEMM (128->10 padded 16) + logits, aggregate + fused pool
  k_mm<C2, 16, 1, C3><<<GB, 256, 0, stream>>>(Xc, W3p, H3b, as3, ad3, als, ald);
  k_agg3<<<NB, 256, 0, stream>>>(rowptr, srcs, H3b, als, ald, b3, pooled, batch);

  // log_softmax; output = [log_softmax | pooled]
  k_lsm<<<(NGRAPH + 255) / 256, 256, 0, stream>>>(pooled, (float*)d_out);
}